// Round 8
// baseline (261.291 us; speedup 1.0000x reference)
//
#include <hip/hip_runtime.h>
#include <hip/hip_bf16.h>

// LSTMAggregator — ROUND 13: exact-3-tile grid + low-pressure epilogue.
// R12 wall arithmetic closed: 1563 tiles / 512 blocks = 3.05 -> 51 blocks ran
// a 4th tile (~25 us straggler phase; 106 us = prologue + 4*T_tile exactly).
// Fix: GRID=521 (1563 = 3*521) — every block does exactly 3 tiles. 9 CUs get
// a 3rd resident block; at ~50% issue-idle they absorb it in stall slots.
// R12 also re-grew FETCH(+23MB)/WRITE(+15MB): epilogue spill (48-reg bW spike
// on top of 96 pinned forward-weight regs, allocator stuck at VGPR=128).
// Fix: per-gate sequential backward weights (16-reg spike, xa re-read from
// LDS per gate). VALUBusy 31% is now ~all transcendental-pipe (80 trans/
// thread/step) — that is the next target if scheduling closes.
//   A-frag: A[m=lane&15][k=(lane>>4)*8+j]   B-frag: B[k][n=lane&15]=W[row][k]
//   C/D: row(node-in-group)=(lane>>4)*4+reg, col=lane&15

#define NN 50000
#define KK 10
#define FF 128
#define HH 64

// ws layout (bf16 elements)
#define WS_WIH_F 0
#define WS_WHH_F 32768
#define WS_WIH_B 49152

#define NPB 32        // nodes per tile
#define NT 1563       // ceil(NN / NPB) = 3 * 521
#define GRID 521      // persistent blocks: exactly 3 tiles each
#define HS 72         // h_lds row stride (shorts)

typedef __bf16 bf16x8 __attribute__((ext_vector_type(8)));
typedef float f32x4 __attribute__((ext_vector_type(4)));
typedef float f32x2 __attribute__((ext_vector_type(2)));

#if __has_builtin(__builtin_amdgcn_exp2f)
#define EXP2(x) __builtin_amdgcn_exp2f(x)
#else
#define EXP2(x) exp2f(x)
#endif

__device__ __forceinline__ float fast_sig(float x) {
    float e = EXP2(x * -1.44269504f);
    return __builtin_amdgcn_rcpf(1.0f + e);
}
__device__ __forceinline__ float fast_tanh(float x) {
    float e = EXP2(x * 2.88539008f);
    return 1.0f - 2.0f * __builtin_amdgcn_rcpf(e + 1.0f);
}
__device__ __forceinline__ f32x2 sig2(f32x2 x) {
    f32x2 t = x * -1.44269504f;                       // v_pk_mul
    f32x2 e = {EXP2(t.x), EXP2(t.y)};
    f32x2 d = e + 1.0f;                               // v_pk_add
    return (f32x2){__builtin_amdgcn_rcpf(d.x), __builtin_amdgcn_rcpf(d.y)};
}
__device__ __forceinline__ f32x2 tanh2(f32x2 x) {
    f32x2 t = x * 2.88539008f;
    f32x2 e = {EXP2(t.x), EXP2(t.y)};
    f32x2 d = e + 1.0f;
    f32x2 r = {__builtin_amdgcn_rcpf(d.x), __builtin_amdgcn_rcpf(d.y)};
    return 1.0f - 2.0f * r;                           // v_pk_fma
}

__global__ void cvt_weights_kernel(const float* __restrict__ Wih_f,
                                   const float* __restrict__ Whh_f,
                                   const float* __restrict__ Wih_b,
                                   __bf16* __restrict__ ws) {
    int i = blockIdx.x * 256 + threadIdx.x;          // 32768 threads
    ws[WS_WIH_F + i] = (__bf16)Wih_f[i];
    if (i < 16384) ws[WS_WHH_F + i] = (__bf16)Whh_f[i];
    ws[WS_WIH_B + i] = (__bf16)Wih_b[i];
}

__global__ __launch_bounds__(256, 2) void lstm_agg_kernel(
    const int* __restrict__ nidx,
    const float* __restrict__ tab,
    const float* __restrict__ bih_f,
    const float* __restrict__ bhh_f,
    const float* __restrict__ bih_b,
    const float* __restrict__ bhh_b,
    const __bf16* __restrict__ ws,
    float* __restrict__ out)
{
    __shared__ __bf16 x_lds[2][NPB * FF];   // 2 x 8 KB bf16, 16B-slot swizzled
    __shared__ __bf16 h_lds[2][NPB * HS];   // 2 x 4.5 KB, double-buffered
    __shared__ int    gq[NPB][KK];          // 1.25 KB        (total 26.9 KB)

    const int tid  = threadIdx.x;
    const int w    = tid >> 6;        // wave id: owns units w*16..w*16+15
    const int lane = tid & 63;
    const int q    = lane >> 4;
    const int c    = lane & 15;
    const int koff = q * 8;
    const int sw = (c & 7) << 4;      // frag-read de-swizzle

    // x staging: thread -> (row = tid>>3, part = tid&7): 64 B f32 each
    const int srow  = tid >> 3;
    const int spart = tid & 7;
    const int swW   = (srow & 7) << 4;

    f32x4 G[4];   // in-flight gather registers (T14 issue-early / write-late)
    auto stage_load = [&](int kidx) {
        const float* src = tab + (size_t)gq[srow][kidx] * FF + spart * 16;
#pragma unroll
        for (int j = 0; j < 4; ++j) G[j] = *(const f32x4*)(src + j * 4);
    };
    auto stage_write = [&](int b) {
        bf16x8 v0, v1;
#pragma unroll
        for (int e = 0; e < 4; ++e) {
            v0[e]     = (__bf16)G[0][e];
            v0[4 + e] = (__bf16)G[1][e];
            v1[e]     = (__bf16)G[2][e];
            v1[4 + e] = (__bf16)G[3][e];
        }
        char* row = (char*)(x_lds[b] + srow * FF);
        *(bf16x8*)(row + ((spart * 32)      ^ swW)) = v0;
        *(bf16x8*)(row + ((spart * 32 + 16) ^ swW)) = v1;
    };

    // weight B-fragments + biases: register-resident across ALL tiles
    bf16x8 bWih[4][4], bWhh[4][2];
#pragma unroll
    for (int g = 0; g < 4; ++g) {
        int row = (g * 4 + w) * 16 + c;        // gate row g*64 + w*16 + c
#pragma unroll
        for (int kk = 0; kk < 4; ++kk)
            bWih[g][kk] = *(const bf16x8*)(ws + WS_WIH_F + row * FF + kk * 32 + koff);
#pragma unroll
        for (int kk = 0; kk < 2; ++kk)
            bWhh[g][kk] = *(const bf16x8*)(ws + WS_WHH_F + row * HH + kk * 32 + koff);
    }
    float bias[4];
#pragma unroll
    for (int g = 0; g < 4; ++g) {
        int u = g * 64 + w * 16 + c;
        bias[g] = bih_f[u] + bhh_f[u];
    }

    for (int tile = blockIdx.x; tile < NT; tile += GRID) {
        const int node_base = tile * NPB;

        __syncthreads();   // previous tile fully retired before gq overwrite
        for (int i = tid; i < NPB * KK; i += 256) {
            int r = i / KK, k = i - r * KK;
            int node = min(node_base + r, NN - 1);
            gq[r][k] = nidx[node * KK + k];
        }
        __syncthreads();   // gq visible

        stage_load(0);
        __builtin_amdgcn_sched_barrier(0);
        stage_write(0);    // vmcnt wait inserted here
        __syncthreads();   // x_0 visible

        f32x4 acc[4][2];      // [gate][node-group]
        float cst[2][4];      // cell state
#pragma unroll
        for (int r = 0; r < 2; ++r)
#pragma unroll
            for (int e = 0; e < 4; ++e) cst[r][e] = 0.0f;

#pragma unroll 2
        for (int k = 0; k < KK; ++k) {
            const int cur = k & 1;
            // issue next step's gather FIRST; fence so it cannot be sunk.
            if (k + 1 < KK) {
                stage_load(k + 1);
                __builtin_amdgcn_sched_barrier(0);
            }

#pragma unroll
            for (int g = 0; g < 4; ++g)
#pragma unroll
                for (int r = 0; r < 2; ++r)
                    acc[g][r] = (f32x4){bias[g], bias[g], bias[g], bias[g]};

            __builtin_amdgcn_s_setprio(1);
            const char* xb = (const char*)x_lds[cur];
#pragma unroll
            for (int r = 0; r < 2; ++r) {
                const char* rp = xb + (r * 16 + c) * 256;
                bf16x8 xa[4];
#pragma unroll
                for (int kk = 0; kk < 4; ++kk)
                    xa[kk] = *(const bf16x8*)(rp + ((kk * 64 + q * 16) ^ sw));
#pragma unroll
                for (int g = 0; g < 4; ++g)
#pragma unroll
                    for (int kk = 0; kk < 4; ++kk)
                        acc[g][r] = __builtin_amdgcn_mfma_f32_16x16x32_bf16(
                            xa[kk], bWih[g][kk], acc[g][r], 0, 0, 0);
            }
            if (k > 0) {
                const __bf16* hb = h_lds[(k - 1) & 1];
#pragma unroll
                for (int r = 0; r < 2; ++r) {
                    bf16x8 ha[2];
#pragma unroll
                    for (int kk = 0; kk < 2; ++kk)
                        ha[kk] = *(const bf16x8*)(hb + (r * 16 + c) * HS + kk * 32 + koff);
#pragma unroll
                    for (int g = 0; g < 4; ++g)
#pragma unroll
                        for (int kk = 0; kk < 2; ++kk)
                            acc[g][r] = __builtin_amdgcn_mfma_f32_16x16x32_bf16(
                                ha[kk], bWhh[g][kk], acc[g][r], 0, 0, 0);
                }
            }
            __builtin_amdgcn_s_setprio(0);

            const bool last = (k == KK - 1);
            __bf16* hw = h_lds[k & 1];
#pragma unroll
            for (int r = 0; r < 2; ++r)
#pragma unroll
                for (int p = 0; p < 2; ++p) {     // reg pairs -> packed f32 math
                    f32x2 ai = {acc[0][r][2 * p], acc[0][r][2 * p + 1]};
                    f32x2 af = {acc[1][r][2 * p], acc[1][r][2 * p + 1]};
                    f32x2 ag = {acc[2][r][2 * p], acc[2][r][2 * p + 1]};
                    f32x2 ao = {acc[3][r][2 * p], acc[3][r][2 * p + 1]};
                    f32x2 gi = sig2(ai);
                    f32x2 gf = sig2(af);
                    f32x2 gg = tanh2(ag);
                    f32x2 go = sig2(ao);
                    f32x2 cc = {cst[r][2 * p], cst[r][2 * p + 1]};
                    f32x2 cn = gf * cc + gi * gg;        // v_pk_mul + v_pk_fma
                    cst[r][2 * p]     = cn.x;
                    cst[r][2 * p + 1] = cn.y;
                    f32x2 h = go * tanh2(cn);
                    hw[(r * 16 + q * 4 + 2 * p)     * HS + w * 16 + c] = (__bf16)h.x;
                    hw[(r * 16 + q * 4 + 2 * p + 1) * HS + w * 16 + c] = (__bf16)h.y;
                    if (last) {
                        int node = node_base + r * 16 + q * 4 + 2 * p;
                        if (node < NN)     out[(size_t)node * 128 + w * 16 + c] = h.x;
                        if (node + 1 < NN) out[(size_t)(node + 1) * 128 + w * 16 + c] = h.y;
                    }
                }

            // write-late: vmcnt drain for G + bf16 LDS write of x_{k+1}
            if (k + 1 < KK) stage_write(cur ^ 1);
            __syncthreads();
        }

        // ---- backward direction: one step on x[:,9] (in x_lds[1]), zero
        // state. Per-gate sequential weight loads: 16-reg spike instead of 48
        // (R12's epilogue spilled against the 96 pinned forward-weight regs).
        {
            const int gb[3] = {0, 2, 3};    // gates i, g, o (f irrelevant: c0=0)
            const char* xb = (const char*)x_lds[(KK - 1) & 1];
            f32x4 ab[3][2];
#pragma unroll
            for (int j = 0; j < 3; ++j) {
                int row = (gb[j] * 4 + w) * 16 + c;
                bf16x8 bW[4];
#pragma unroll
                for (int kk = 0; kk < 4; ++kk)
                    bW[kk] = *(const bf16x8*)(ws + WS_WIH_B + row * FF + kk * 32 + koff);
                int u = gb[j] * 64 + w * 16 + c;
                float bb = bih_b[u] + bhh_b[u];
#pragma unroll
                for (int r = 0; r < 2; ++r) {
                    f32x4 a = (f32x4){bb, bb, bb, bb};
                    const char* rp = xb + (r * 16 + c) * 256;
#pragma unroll
                    for (int kk = 0; kk < 4; ++kk) {
                        bf16x8 xa = *(const bf16x8*)(rp + ((kk * 64 + q * 16) ^ sw));
                        a = __builtin_amdgcn_mfma_f32_16x16x32_bf16(xa, bW[kk], a, 0, 0, 0);
                    }
                    ab[j][r] = a;
                }
            }
#pragma unroll
            for (int r = 0; r < 2; ++r)
#pragma unroll
                for (int reg = 0; reg < 4; ++reg) {
                    float gi = fast_sig(ab[0][r][reg]);
                    float gg = fast_tanh(ab[1][r][reg]);
                    float go = fast_sig(ab[2][r][reg]);
                    float hb2 = go * fast_tanh(gi * gg);
                    int node = node_base + r * 16 + q * 4 + reg;
                    if (node < NN) out[(size_t)node * 128 + 64 + w * 16 + c] = hb2;
                }
        }
    }
}

extern "C" void kernel_launch(void* const* d_in, const int* in_sizes, int n_in,
                              void* d_out, int out_size, void* d_ws, size_t ws_size,
                              hipStream_t stream) {
    const int*   nidx  = (const int*)d_in[0];
    const float* tab   = (const float*)d_in[1];
    const float* Wih_f = (const float*)d_in[2];
    const float* Whh_f = (const float*)d_in[3];
    const float* bih_f = (const float*)d_in[4];
    const float* bhh_f = (const float*)d_in[5];
    const float* Wih_b = (const float*)d_in[6];
    // d_in[7] = Whh_b: mathematically unused (h0 = 0 for the backward stream)
    const float* bih_b = (const float*)d_in[8];
    const float* bhh_b = (const float*)d_in[9];
    __bf16* ws  = (__bf16*)d_ws;      // 160 KB scratch
    float*  out = (float*)d_out;      // output is f32

    hipLaunchKernelGGL(cvt_weights_kernel, dim3(32768 / 256), dim3(256), 0, stream,
                       Wih_f, Whh_f, Wih_b, ws);

    hipLaunchKernelGGL(lstm_agg_kernel, dim3(GRID), dim3(256), 0, stream,
                       nidx, tab, bih_f, bhh_f, bih_b, bhh_b, ws, out);
}

// Round 9
// 228.619 us; speedup vs baseline: 1.1429x; 1.1429x over previous
//
#include <hip/hip_runtime.h>
#include <hip/hip_bf16.h>

// LSTMAggregator — ROUND 14: 2-deep gather pipeline + counted-wait barriers.
// R13 lesson: GRID=521 straggler-regressed (3-block CUs serialize: issue
// capacity, not stall slots, is the binding resource) -> back to GRID=512.
// R12's 25us/tile = 30 steps x ~2000cyc, vs ~650cyc issue work: the gap is
// (a) gather latency (~900cyc) under only ~650cyc of cover, and (b)
// __syncthreads' vmcnt(0) drain killing any run-ahead each step (the §5
// barrier-drain stall). Fix = T3/T4: two gather reg-sets GA/GB, issue k+2 at
// step k top; stage_write consumes the OLDER set (compiler emits vmcnt(4),
// newer 4 loads stay in flight); in-loop barrier = ds_write -> s_waitcnt
// lgkmcnt(0) -> raw s_barrier -> sched_barrier(0) (LDS visible, global loads
// survive) -> issue-to-consume window ~2 steps > HBM latency. Tile
// boundaries keep plain __syncthreads. Parity static under unroll 2.
//   A-frag: A[m=lane&15][k=(lane>>4)*8+j]   B-frag: B[k][n=lane&15]=W[row][k]
//   C/D: row(node-in-group)=(lane>>4)*4+reg, col=lane&15

#define NN 50000
#define KK 10
#define FF 128
#define HH 64

// ws layout (bf16 elements)
#define WS_WIH_F 0
#define WS_WHH_F 32768
#define WS_WIH_B 49152

#define NPB 32        // nodes per tile
#define NT 1563       // ceil(NN / NPB)
#define GRID 512      // persistent blocks: 2 per CU (R12 proven)
#define HS 72         // h_lds row stride (shorts)

typedef __bf16 bf16x8 __attribute__((ext_vector_type(8)));
typedef float f32x4 __attribute__((ext_vector_type(4)));
typedef float f32x2 __attribute__((ext_vector_type(2)));

#if __has_builtin(__builtin_amdgcn_exp2f)
#define EXP2(x) __builtin_amdgcn_exp2f(x)
#else
#define EXP2(x) exp2f(x)
#endif

__device__ __forceinline__ float fast_sig(float x) {
    float e = EXP2(x * -1.44269504f);
    return __builtin_amdgcn_rcpf(1.0f + e);
}
__device__ __forceinline__ float fast_tanh(float x) {
    float e = EXP2(x * 2.88539008f);
    return 1.0f - 2.0f * __builtin_amdgcn_rcpf(e + 1.0f);
}
__device__ __forceinline__ f32x2 sig2(f32x2 x) {
    f32x2 t = x * -1.44269504f;                       // v_pk_mul
    f32x2 e = {EXP2(t.x), EXP2(t.y)};
    f32x2 d = e + 1.0f;                               // v_pk_add
    return (f32x2){__builtin_amdgcn_rcpf(d.x), __builtin_amdgcn_rcpf(d.y)};
}
__device__ __forceinline__ f32x2 tanh2(f32x2 x) {
    f32x2 t = x * 2.88539008f;
    f32x2 e = {EXP2(t.x), EXP2(t.y)};
    f32x2 d = e + 1.0f;
    f32x2 r = {__builtin_amdgcn_rcpf(d.x), __builtin_amdgcn_rcpf(d.y)};
    return 1.0f - 2.0f * r;                           // v_pk_fma
}

__global__ void cvt_weights_kernel(const float* __restrict__ Wih_f,
                                   const float* __restrict__ Whh_f,
                                   const float* __restrict__ Wih_b,
                                   __bf16* __restrict__ ws) {
    int i = blockIdx.x * 256 + threadIdx.x;          // 32768 threads
    ws[WS_WIH_F + i] = (__bf16)Wih_f[i];
    if (i < 16384) ws[WS_WHH_F + i] = (__bf16)Whh_f[i];
    ws[WS_WIH_B + i] = (__bf16)Wih_b[i];
}

// gather-set load: 4x global_load_dwordx4 into the given reg set
#define STAGE_LOAD(Gs, kidx)                                                  \
    do {                                                                      \
        const float* _src = tab + (size_t)gq[srow][(kidx)] * FF + spart * 16; \
        _Pragma("unroll")                                                     \
        for (int _j = 0; _j < 4; ++_j) Gs[_j] = *(const f32x4*)(_src + _j * 4);\
    } while (0)

// convert + swizzled LDS write of a gather set (compiler emits the counted
// vmcnt for exactly this set's loads; newer set stays in flight)
#define STAGE_WRITE(Gs, b)                                                    \
    do {                                                                      \
        bf16x8 _v0, _v1;                                                      \
        _Pragma("unroll")                                                     \
        for (int _e = 0; _e < 4; ++_e) {                                      \
            _v0[_e]     = (__bf16)Gs[0][_e];                                  \
            _v0[4 + _e] = (__bf16)Gs[1][_e];                                  \
            _v1[_e]     = (__bf16)Gs[2][_e];                                  \
            _v1[4 + _e] = (__bf16)Gs[3][_e];                                  \
        }                                                                     \
        char* _row = (char*)(x_lds[(b)] + srow * FF);                         \
        *(bf16x8*)(_row + ((spart * 32)      ^ swW)) = _v0;                   \
        *(bf16x8*)(_row + ((spart * 32 + 16) ^ swW)) = _v1;                   \
    } while (0)

// in-loop barrier: LDS writes visible, global loads stay in flight
#define STEP_BARRIER()                                                        \
    do {                                                                      \
        asm volatile("s_waitcnt lgkmcnt(0)" ::: "memory");                    \
        __builtin_amdgcn_s_barrier();                                         \
        __builtin_amdgcn_sched_barrier(0);                                    \
    } while (0)

__global__ __launch_bounds__(256, 2) void lstm_agg_kernel(
    const int* __restrict__ nidx,
    const float* __restrict__ tab,
    const float* __restrict__ bih_f,
    const float* __restrict__ bhh_f,
    const float* __restrict__ bih_b,
    const float* __restrict__ bhh_b,
    const __bf16* __restrict__ ws,
    float* __restrict__ out)
{
    __shared__ __bf16 x_lds[2][NPB * FF];   // 2 x 8 KB bf16, 16B-slot swizzled
    __shared__ __bf16 h_lds[2][NPB * HS];   // 2 x 4.5 KB, double-buffered
    __shared__ int    gq[NPB][KK];          // 1.25 KB        (total 26.9 KB)

    const int tid  = threadIdx.x;
    const int w    = tid >> 6;        // wave id: owns units w*16..w*16+15
    const int lane = tid & 63;
    const int q    = lane >> 4;
    const int c    = lane & 15;
    const int koff = q * 8;
    const int sw = (c & 7) << 4;      // frag-read de-swizzle

    // x staging: thread -> (row = tid>>3, part = tid&7): 64 B f32 each
    const int srow  = tid >> 3;
    const int spart = tid & 7;
    const int swW   = (srow & 7) << 4;

    f32x4 GA[4], GB[4];   // 2-deep in-flight gather sets (even k / odd k)

    // weight B-fragments + biases: register-resident across ALL tiles
    bf16x8 bWih[4][4], bWhh[4][2];
#pragma unroll
    for (int g = 0; g < 4; ++g) {
        int row = (g * 4 + w) * 16 + c;        // gate row g*64 + w*16 + c
#pragma unroll
        for (int kk = 0; kk < 4; ++kk)
            bWih[g][kk] = *(const bf16x8*)(ws + WS_WIH_F + row * FF + kk * 32 + koff);
#pragma unroll
        for (int kk = 0; kk < 2; ++kk)
            bWhh[g][kk] = *(const bf16x8*)(ws + WS_WHH_F + row * HH + kk * 32 + koff);
    }
    float bias[4];
#pragma unroll
    for (int g = 0; g < 4; ++g) {
        int u = g * 64 + w * 16 + c;
        bias[g] = bih_f[u] + bhh_f[u];
    }

    for (int tile = blockIdx.x; tile < NT; tile += GRID) {
        const int node_base = tile * NPB;

        __syncthreads();   // previous tile fully retired before gq overwrite
        for (int i = tid; i < NPB * KK; i += 256) {
            int r = i / KK, k = i - r * KK;
            int node = min(node_base + r, NN - 1);
            gq[r][k] = nidx[node * KK + k];
        }
        __syncthreads();   // gq visible

        STAGE_LOAD(GA, 0);          // k0
        STAGE_LOAD(GB, 1);          // k1 — stays in flight across barrier
        __builtin_amdgcn_sched_barrier(0);
        STAGE_WRITE(GA, 0);         // vmcnt(4) retires GA only
        STEP_BARRIER();             // x_0 visible; GB loads still outstanding

        f32x4 acc[4][2];      // [gate][node-group]
        float cst[2][4];      // cell state
#pragma unroll
        for (int r = 0; r < 2; ++r)
#pragma unroll
            for (int e = 0; e < 4; ++e) cst[r][e] = 0.0f;

#pragma unroll 2
        for (int k = 0; k < KK; ++k) {
            const int cur = k & 1;
            // issue loads for k+2 into the set freed by this step's write
            if (k + 2 < KK) {
                if ((k & 1) == 0) STAGE_LOAD(GA, k + 2);
                else              STAGE_LOAD(GB, k + 2);
                __builtin_amdgcn_sched_barrier(0);
            }

#pragma unroll
            for (int g = 0; g < 4; ++g)
#pragma unroll
                for (int r = 0; r < 2; ++r)
                    acc[g][r] = (f32x4){bias[g], bias[g], bias[g], bias[g]};

            __builtin_amdgcn_s_setprio(1);
            const char* xb = (const char*)x_lds[cur];
#pragma unroll
            for (int r = 0; r < 2; ++r) {
                const char* rp = xb + (r * 16 + c) * 256;
                bf16x8 xa[4];
#pragma unroll
                for (int kk = 0; kk < 4; ++kk)
                    xa[kk] = *(const bf16x8*)(rp + ((kk * 64 + q * 16) ^ sw));
#pragma unroll
                for (int g = 0; g < 4; ++g)
#pragma unroll
                    for (int kk = 0; kk < 4; ++kk)
                        acc[g][r] = __builtin_amdgcn_mfma_f32_16x16x32_bf16(
                            xa[kk], bWih[g][kk], acc[g][r], 0, 0, 0);
            }
            if (k > 0) {
                const __bf16* hb = h_lds[(k - 1) & 1];
#pragma unroll
                for (int r = 0; r < 2; ++r) {
                    bf16x8 ha[2];
#pragma unroll
                    for (int kk = 0; kk < 2; ++kk)
                        ha[kk] = *(const bf16x8*)(hb + (r * 16 + c) * HS + kk * 32 + koff);
#pragma unroll
                    for (int g = 0; g < 4; ++g)
#pragma unroll
                        for (int kk = 0; kk < 2; ++kk)
                            acc[g][r] = __builtin_amdgcn_mfma_f32_16x16x32_bf16(
                                ha[kk], bWhh[g][kk], acc[g][r], 0, 0, 0);
                }
            }
            __builtin_amdgcn_s_setprio(0);

            const bool last = (k == KK - 1);
            __bf16* hw = h_lds[k & 1];
#pragma unroll
            for (int r = 0; r < 2; ++r)
#pragma unroll
                for (int p = 0; p < 2; ++p) {     // reg pairs -> packed f32 math
                    f32x2 ai = {acc[0][r][2 * p], acc[0][r][2 * p + 1]};
                    f32x2 af = {acc[1][r][2 * p], acc[1][r][2 * p + 1]};
                    f32x2 ag = {acc[2][r][2 * p], acc[2][r][2 * p + 1]};
                    f32x2 ao = {acc[3][r][2 * p], acc[3][r][2 * p + 1]};
                    f32x2 gi = sig2(ai);
                    f32x2 gf = sig2(af);
                    f32x2 gg = tanh2(ag);
                    f32x2 go = sig2(ao);
                    f32x2 cc = {cst[r][2 * p], cst[r][2 * p + 1]};
                    f32x2 cn = gf * cc + gi * gg;        // v_pk_mul + v_pk_fma
                    cst[r][2 * p]     = cn.x;
                    cst[r][2 * p + 1] = cn.y;
                    f32x2 h = go * tanh2(cn);
                    hw[(r * 16 + q * 4 + 2 * p)     * HS + w * 16 + c] = (__bf16)h.x;
                    hw[(r * 16 + q * 4 + 2 * p + 1) * HS + w * 16 + c] = (__bf16)h.y;
                    if (last) {
                        int node = node_base + r * 16 + q * 4 + 2 * p;
                        if (node < NN)     out[(size_t)node * 128 + w * 16 + c] = h.x;
                        if (node + 1 < NN) out[(size_t)(node + 1) * 128 + w * 16 + c] = h.y;
                    }
                }

            // write-late: the OLDER set (data k+1) -> LDS; newer stays in flight
            if (k + 1 < KK) {
                if (((k + 1) & 1) == 0) STAGE_WRITE(GA, 0);
                else                    STAGE_WRITE(GB, 1);
            }
            STEP_BARRIER();
        }

        // ---- backward direction: one step on x[:,9] (in x_lds[1]), zero
        // state. Per-gate sequential weight loads (16-reg spike).
        {
            const int gb[3] = {0, 2, 3};    // gates i, g, o (f irrelevant: c0=0)
            const char* xb = (const char*)x_lds[(KK - 1) & 1];
            f32x4 ab[3][2];
#pragma unroll
            for (int j = 0; j < 3; ++j) {
                int row = (gb[j] * 4 + w) * 16 + c;
                bf16x8 bW[4];
#pragma unroll
                for (int kk = 0; kk < 4; ++kk)
                    bW[kk] = *(const bf16x8*)(ws + WS_WIH_B + row * FF + kk * 32 + koff);
                int u = gb[j] * 64 + w * 16 + c;
                float bb = bih_b[u] + bhh_b[u];
#pragma unroll
                for (int r = 0; r < 2; ++r) {
                    f32x4 a = (f32x4){bb, bb, bb, bb};
                    const char* rp = xb + (r * 16 + c) * 256;
#pragma unroll
                    for (int kk = 0; kk < 4; ++kk) {
                        bf16x8 xa = *(const bf16x8*)(rp + ((kk * 64 + q * 16) ^ sw));
                        a = __builtin_amdgcn_mfma_f32_16x16x32_bf16(xa, bW[kk], a, 0, 0, 0);
                    }
                    ab[j][r] = a;
                }
            }
#pragma unroll
            for (int r = 0; r < 2; ++r)
#pragma unroll
                for (int reg = 0; reg < 4; ++reg) {
                    float gi = fast_sig(ab[0][r][reg]);
                    float gg = fast_tanh(ab[1][r][reg]);
                    float go = fast_sig(ab[2][r][reg]);
                    float hb2 = go * fast_tanh(gi * gg);
                    int node = node_base + r * 16 + q * 4 + reg;
                    if (node < NN) out[(size_t)node * 128 + 64 + w * 16 + c] = hb2;
                }
        }
    }
}

extern "C" void kernel_launch(void* const* d_in, const int* in_sizes, int n_in,
                              void* d_out, int out_size, void* d_ws, size_t ws_size,
                              hipStream_t stream) {
    const int*   nidx  = (const int*)d_in[0];
    const float* tab   = (const float*)d_in[1];
    const float* Wih_f = (const float*)d_in[2];
    const float* Whh_f = (const float*)d_in[3];
    const float* bih_f = (const float*)d_in[4];
    const float* bhh_f = (const float*)d_in[5];
    const float* Wih_b = (const float*)d_in[6];
    // d_in[7] = Whh_b: mathematically unused (h0 = 0 for the backward stream)
    const float* bih_b = (const float*)d_in[8];
    const float* bhh_b = (const float*)d_in[9];
    __bf16* ws  = (__bf16*)d_ws;      // 160 KB scratch
    float*  out = (float*)d_out;      // output is f32

    hipLaunchKernelGGL(cvt_weights_kernel, dim3(32768 / 256), dim3(256), 0, stream,
                       Wih_f, Whh_f, Wih_b, ws);

    hipLaunchKernelGGL(lstm_agg_kernel, dim3(GRID), dim3(256), 0, stream,
                       nidx, tab, bih_f, bhh_f, bih_b, bhh_b, ws, out);
}